// Round 8
// baseline (317.650 us; speedup 1.0000x reference)
//
#include <hip/hip_runtime.h>

// Steerable pyramid, depthwise convs, NHWC fp32, C=16 (= 4 x float4).
// Scale-0 kernels use a COLUMN-SWEEP pending-accumulator structure:
// each thread owns one (x, c4) column; per step it loads ONE input row's
// 9 taps and updates 9 pending output accumulators (output y = r-4+j uses
// filter row 8-j, statically known). acc[0] retires each step -> store,
// shift register (static), zero acc[8]. 9 loads per ~2600 compute cycles
// -> load latency self-hidden in-wave; no re-loading of rows.

static __device__ __forceinline__ float4 f4z() { return make_float4(0.f, 0.f, 0.f, 0.f); }

static __device__ __forceinline__ float4 fmaf4(float f, float4 v, float4 a) {
    a.x = fmaf(f, v.x, a.x);
    a.y = fmaf(f, v.y, a.y);
    a.z = fmaf(f, v.z, a.z);
    a.w = fmaf(f, v.w, a.w);
    return a;
}

typedef __attribute__((ext_vector_type(4))) float f32x4;

static __device__ __forceinline__ void nt_store(float4* p, float4 v) {
    __builtin_nontemporal_store(*(const f32x4*)&v, (f32x4*)p);
}

// ---------------------------------------------------------------- pad helpers

__global__ __launch_bounds__(256) void pad_copy_img(
    const float4* __restrict__ src, float4* __restrict__ dst)
{
    const int W = 256, P = 4, Wp = 264;
    int n = blockIdx.x & 7;
    int q = blockIdx.x >> 3;                 // 1089 per n
    int e = q * 256 + threadIdx.x;           // < 264*264*4 exactly
    int c4 = e & 3;
    int pix = e >> 2;
    int yp = pix / Wp;
    int xp = pix - yp * Wp;
    int y = yp - P, x = xp - P;
    bool ok = ((unsigned)y < (unsigned)W) && ((unsigned)x < (unsigned)W);
    int yc = min(max(y, 0), W - 1), xc = min(max(x, 0), W - 1);
    float4 v = src[(((n * W + yc) * W + xc) << 2) + c4];
    if (!ok) v = f4z();
    dst[((size_t)n * Wp * Wp + pix) * 4 + c4] = v;
}

__global__ __launch_bounds__(256) void zero_pads_all(
    float4* __restrict__ L0, float4* __restrict__ L1,
    float4* __restrict__ L2, float4* __restrict__ L3)
{
    int b = blockIdx.x;
    float4* buf; int W;
    if (b < 1056)      { buf = L0; W = 256; }
    else if (b < 1600) { buf = L1; W = 128; b -= 1056; }
    else if (b < 1888) { buf = L2; W = 64;  b -= 1600; }
    else               { buf = L3; W = 32;  b -= 1888; }
    int Wp = W + 16;
    int perN = 16 * Wp + 16 * W;
    int tid = b * 256 + threadIdx.x;
    int c4 = tid & 3;
    int p  = tid >> 2;
    int n  = p / perN;
    int r  = p - n * perN;
    int y, x;
    if (r < 16 * Wp) {
        int row = r / Wp;
        x = r - row * Wp;
        y = (row < 8) ? row : (W + row);
    } else {
        int q = r - 16 * Wp;
        y = 8 + (q >> 4);
        int xi = q & 15;
        x = (xi < 8) ? xi : (Wp - 16 + xi);
    }
    buf[((size_t)(n * Wp + y) * Wp + x) * 4 + c4] = f4z();
}

// ------------------------------------------------- scale-0 column-sweep convs

// hi0 + lo0 from padded image (pad 4, Wp=264). 256 thr = 64 xi x 4 c4.
// grid: 8n x 4 xt x 8 yt (YSPAN=32).  b: n=b&7, q=b>>3, xt=q>>3, yt=q&7.
__global__ __launch_bounds__(256, 1) void dual_col(
    const float4* __restrict__ in,   // 264 wide, pad 4
    float4* __restrict__ hi0,        // flat 256 (d_out, nt)
    float4* __restrict__ lo0,        // 272 wide, pad 8 (ws, cached)
    const float* __restrict__ fh, const float* __restrict__ fl)
{
    const int Wp = 264;
    int n = blockIdx.x & 7;
    int q = blockIdx.x >> 3;
    int xt = q >> 3, yt = q & 7;
    int t = threadIdx.x;
    int c4 = t & 3;
    int x  = xt * 64 + (t >> 2);     // logical output x
    int y0 = yt * 32;

    // input row r (logical), first r = y0-4 -> padded row y0; tap col x-4+d -> padded x+d
    const float4* rp = in + ((size_t)(n * Wp + y0) * Wp + x) * 4 + c4;
    const size_t rstep = (size_t)Wp * 4;

    float4 acc[9][2];
    #pragma unroll
    for (int j = 0; j < 9; ++j) { acc[j][0] = f4z(); acc[j][1] = f4z(); }

#define DC_STEP                                                     \
    {                                                               \
        float4 v[9];                                                \
        _Pragma("unroll")                                           \
        for (int d = 0; d < 9; ++d) v[d] = rp[d * 4];               \
        rp += rstep;                                                \
        _Pragma("unroll")                                           \
        for (int j = 0; j < 9; ++j) {                               \
            const float* wh = fh + (8 - j) * 9;                     \
            const float* wl = fl + (8 - j) * 9;                     \
            _Pragma("unroll")                                       \
            for (int dx = 0; dx < 9; ++dx) {                        \
                acc[j][0] = fmaf4(wh[dx], v[dx], acc[j][0]);        \
                acc[j][1] = fmaf4(wl[dx], v[dx], acc[j][1]);        \
            }                                                       \
        }                                                           \
    }
#define DC_SHIFT                                                    \
    {                                                               \
        _Pragma("unroll")                                           \
        for (int j = 0; j < 8; ++j) {                               \
            acc[j][0] = acc[j + 1][0];                              \
            acc[j][1] = acc[j + 1][1];                              \
        }                                                           \
        acc[8][0] = f4z(); acc[8][1] = f4z();                       \
    }

    #pragma unroll 1
    for (int s = 0; s < 8; ++s) { DC_STEP; DC_SHIFT; }   // fill (no store)

    size_t hidx = ((size_t)(n * 256 + y0) * 256 + x) * 4 + c4;
    size_t lidx = ((size_t)(n * 272 + y0 + 8) * 272 + (x + 8)) * 4 + c4;
    #pragma unroll 1
    for (int s = 0; s < 32; ++s) {
        DC_STEP;
        nt_store(&hi0[hidx], acc[0][0]);
        lo0[lidx] = acc[0][1];
        hidx += 256 * 4;
        lidx += 272 * 4;
        DC_SHIFT;
    }
#undef DC_STEP
#undef DC_SHIFT
}

// 4 band convs at scale 0 from L0 (pad 8, Wp=272). Same geometry as dual_col.
__global__ __launch_bounds__(256, 1) void bands_col0(
    const float4* __restrict__ in,   // 272 wide, pad 8
    float4* __restrict__ b0, float4* __restrict__ b1,
    float4* __restrict__ b2, float4* __restrict__ b3,
    const float* __restrict__ bf)    // 4*81 contiguous
{
    const int Wp = 272;
    int n = blockIdx.x & 7;
    int q = blockIdx.x >> 3;
    int xt = q >> 3, yt = q & 7;
    int t = threadIdx.x;
    int c4 = t & 3;
    int x  = xt * 64 + (t >> 2);
    int y0 = yt * 32;

    // first input row r = y0-4 -> padded y0+4; tap col x-4+d -> padded x+4+d
    const float4* rp = in + ((size_t)(n * Wp + y0 + 4) * Wp + (x + 4)) * 4 + c4;
    const size_t rstep = (size_t)Wp * 4;

    float4 acc[9][4];
    #pragma unroll
    for (int j = 0; j < 9; ++j)
        #pragma unroll
        for (int f = 0; f < 4; ++f) acc[j][f] = f4z();

#define BC_STEP                                                     \
    {                                                               \
        float4 v[9];                                                \
        _Pragma("unroll")                                           \
        for (int d = 0; d < 9; ++d) v[d] = rp[d * 4];               \
        rp += rstep;                                                \
        _Pragma("unroll")                                           \
        for (int j = 0; j < 9; ++j) {                               \
            const float* wr = bf + (8 - j) * 9;                     \
            _Pragma("unroll")                                       \
            for (int dx = 0; dx < 9; ++dx) {                        \
                acc[j][0] = fmaf4(wr[dx],       v[dx], acc[j][0]);  \
                acc[j][1] = fmaf4(wr[81 + dx],  v[dx], acc[j][1]);  \
                acc[j][2] = fmaf4(wr[162 + dx], v[dx], acc[j][2]);  \
                acc[j][3] = fmaf4(wr[243 + dx], v[dx], acc[j][3]);  \
            }                                                       \
        }                                                           \
    }
#define BC_SHIFT                                                    \
    {                                                               \
        _Pragma("unroll")                                           \
        for (int j = 0; j < 8; ++j)                                 \
            { acc[j][0] = acc[j+1][0]; acc[j][1] = acc[j+1][1];     \
              acc[j][2] = acc[j+1][2]; acc[j][3] = acc[j+1][3]; }   \
        acc[8][0] = f4z(); acc[8][1] = f4z();                       \
        acc[8][2] = f4z(); acc[8][3] = f4z();                       \
    }

    #pragma unroll 1
    for (int s = 0; s < 8; ++s) { BC_STEP; BC_SHIFT; }

    size_t oidx = ((size_t)(n * 256 + y0) * 256 + x) * 4 + c4;
    #pragma unroll 1
    for (int s = 0; s < 32; ++s) {
        BC_STEP;
        nt_store(&b0[oidx], acc[0][0]);
        nt_store(&b1[oidx], acc[0][1]);
        nt_store(&b2[oidx], acc[0][2]);
        nt_store(&b3[oidx], acc[0][3]);
        oidx += 256 * 4;
        BC_SHIFT;
    }
#undef BC_STEP
#undef BC_SHIFT
}

// ---------------------------------------------- 17x17 stride-2 downsample s0

// L0 (pad 8, Wp=272) -> L1 (pad 8, W1=144). 4px/thread sliding window.
// n=b&7, q=b>>3 (64 per n), 2 output rows per block.
__global__ __launch_bounds__(256) void down17_s0(
    const float4* __restrict__ in, float4* __restrict__ lo_out,
    const float* __restrict__ lf)
{
    const int Wp = 272, Wo = 128;
    int n = blockIdx.x & 7;
    int q = blockIdx.x >> 3;
    int t = threadIdx.x;
    int c4 = t & 3;
    int xg = (t >> 2) & 31;
    int ry = t >> 7;
    int yo = q * 2 + ry;
    int xo0 = xg * 4;
    const float4* row = in + ((size_t)(n * Wp + 2 * yo) * Wp + 2 * xo0) * 4 + c4;

    float4 acc[4];
    #pragma unroll
    for (int p = 0; p < 4; ++p) acc[p] = f4z();

    #pragma unroll 1
    for (int dy = 0; dy < 17; ++dy) {
        float4 v[23];
        #pragma unroll
        for (int j = 0; j < 23; ++j) v[j] = row[j * 4];
        #pragma unroll
        for (int dx = 0; dx < 17; ++dx) {
            float w = lf[dy * 17 + dx];
            #pragma unroll
            for (int p = 0; p < 4; ++p)
                acc[p] = fmaf4(w, v[2 * p + dx], acc[p]);
        }
        row += Wp * 4;
    }
    const int W1 = 144;
    #pragma unroll
    for (int p = 0; p < 4; ++p)
        lo_out[((size_t)(n * W1 + yo + 8) * W1 + xo0 + p + 8) * 4 + c4] = acc[p];
}

// ------------------------------------- scales 1..3 fused (round-7 structure)

template <int LOGW>
__global__ __launch_bounds__(256) void scale_fused(
    const float4* __restrict__ in,
    float4* __restrict__ b0, float4* __restrict__ b1,
    float4* __restrict__ b2, float4* __restrict__ b3,
    float4* __restrict__ lo_out,
    const float* __restrict__ bf,    // 4*81 contiguous
    const float* __restrict__ lf,    // 17*17
    int outPad)
{
    const int W = 1 << LOGW, Wp = W + 16;
    const int bandsPerN = (W * W) >> 8;
    int n = blockIdx.x & 7;
    int q = blockIdx.x >> 3;
    int t = threadIdx.x;
    int c4 = t & 3;

    if (q < bandsPerN) {
        int xg = (t >> 2) & (W / 4 - 1);
        int ry = t >> LOGW;
        int y  = q * (256 >> LOGW) + ry;
        int x0 = xg * 4;
        const float4* row = in + ((size_t)(n * Wp + y + 4) * Wp + (x0 + 4)) * 4 + c4;

        float4 acc[4][4];
        #pragma unroll
        for (int p = 0; p < 4; ++p)
            #pragma unroll
            for (int f = 0; f < 4; ++f) acc[p][f] = f4z();

        #pragma unroll 1
        for (int dy = 0; dy < 9; ++dy) {
            float4 v[12];
            #pragma unroll
            for (int j = 0; j < 12; ++j) v[j] = row[j * 4];
            #pragma unroll
            for (int dx = 0; dx < 9; ++dx) {
                int tt = dy * 9 + dx;
                float w0 = bf[tt], w1 = bf[81 + tt], w2 = bf[162 + tt], w3 = bf[243 + tt];
                #pragma unroll
                for (int p = 0; p < 4; ++p) {
                    acc[p][0] = fmaf4(w0, v[p + dx], acc[p][0]);
                    acc[p][1] = fmaf4(w1, v[p + dx], acc[p][1]);
                    acc[p][2] = fmaf4(w2, v[p + dx], acc[p][2]);
                    acc[p][3] = fmaf4(w3, v[p + dx], acc[p][3]);
                }
            }
            row += Wp * 4;
        }
        #pragma unroll
        for (int p = 0; p < 4; ++p) {
            size_t idx = ((size_t)(n * W + y) * W + x0 + p) * 4 + c4;
            nt_store(&b0[idx], acc[p][0]);
            nt_store(&b1[idx], acc[p][1]);
            nt_store(&b2[idx], acc[p][2]);
            nt_store(&b3[idx], acc[p][3]);
        }
    } else {
        const int Wo = W >> 1;
        int q2 = q - bandsPerN;
        int xg = (t >> 2) & (Wo / 4 - 1);
        int ry = t >> (LOGW - 1);
        int yo = q2 * (256 >> (LOGW - 1)) + ry;
        int xo0 = xg * 4;
        const float4* row = in + ((size_t)(n * Wp + 2 * yo) * Wp + 2 * xo0) * 4 + c4;

        float4 acc[4];
        #pragma unroll
        for (int p = 0; p < 4; ++p) acc[p] = f4z();

        #pragma unroll 1
        for (int dy = 0; dy < 17; ++dy) {
            float4 v[23];
            #pragma unroll
            for (int j = 0; j < 23; ++j) v[j] = row[j * 4];
            #pragma unroll
            for (int dx = 0; dx < 17; ++dx) {
                float w = lf[dy * 17 + dx];
                #pragma unroll
                for (int p = 0; p < 4; ++p)
                    acc[p] = fmaf4(w, v[2 * p + dx], acc[p]);
            }
            row += Wp * 4;
        }
        int W1 = Wo + 2 * outPad;
        #pragma unroll
        for (int p = 0; p < 4; ++p)
            lo_out[((size_t)(n * W1 + yo + outPad) * W1 + xo0 + p + outPad) * 4 + c4] = acc[p];
    }
}

// ---------------------------------------------------------------- launch

extern "C" void kernel_launch(void* const* d_in, const int* in_sizes, int n_in,
                              void* d_out, int out_size, void* d_ws, size_t ws_size,
                              hipStream_t stream) {
    const float* image   = (const float*)d_in[0];
    const float* lo0filt = (const float*)d_in[1];
    const float* hi0filt = (const float*)d_in[2];
    const float* lofilt  = (const float*)d_in[3];
    const float* bfilts  = (const float*)d_in[4];
    float* out = (float*)d_out;
    float* ws  = (float*)d_ws;

    const int N = 8, C = 16;
    size_t sz[5];
    const int Ws[5] = {256, 128, 64, 32, 16};
    for (int s = 0; s < 5; ++s) sz[s] = (size_t)N * Ws[s] * Ws[s] * C;

    // Workspace: P0 = image pad4 (264^2); L0..L3 = lo0..lo3 pad8.
    float* P0 = ws;
    float* L0 = P0 + (size_t)N * 264 * 264 * C;
    float* L1 = L0 + (size_t)N * 272 * 272 * C;
    float* L2 = L1 + (size_t)N * 144 * 144 * C;
    float* L3 = L2 + (size_t)N * 80 * 80 * C;

    // Output layout (reversed pyramid, flat):
    // [ lo_final | s=3 b=3..0 | s=2 b=3..0 | s=1 b=3..0 | s=0 b=3..0 | hi0 ]
    float* out_lofinal = out;
    size_t o = sz[4];
    float* band_ptr[4][4];
    for (int s = 3; s >= 0; --s)
        for (int b = 3; b >= 0; --b) { band_ptr[s][b] = out + o; o += sz[s]; }
    float* out_hi0 = out + o;

    // 1. zero pad borders of L0..L3
    zero_pads_all<<<2048, 256, 0, stream>>>(
        (float4*)L0, (float4*)L1, (float4*)L2, (float4*)L3);
    // 2. image -> P0 (pad 4)
    pad_copy_img<<<8 * 1089, 256, 0, stream>>>(
        (const float4*)image, (float4*)P0);
    // 3. hi0 (nt) + lo0 (cached) via column sweep
    dual_col<<<256, 256, 0, stream>>>(
        (const float4*)P0, (float4*)out_hi0, (float4*)L0, hi0filt, lo0filt);
    // 4. lo1 = downsample(lo0)
    down17_s0<<<8 * 64, 256, 0, stream>>>(
        (const float4*)L0, (float4*)L1, lofilt);
    // 5. bands s=0 via column sweep
    bands_col0<<<256, 256, 0, stream>>>(
        (const float4*)L0, (float4*)band_ptr[0][0], (float4*)band_ptr[0][1],
        (float4*)band_ptr[0][2], (float4*)band_ptr[0][3], bfilts);
    // 6..8. scales 1..3 fused
    scale_fused<7><<<8 * (64 + 16), 256, 0, stream>>>(
        (const float4*)L1, (float4*)band_ptr[1][0], (float4*)band_ptr[1][1],
        (float4*)band_ptr[1][2], (float4*)band_ptr[1][3], (float4*)L2,
        bfilts, lofilt, 8);
    scale_fused<6><<<8 * (16 + 4), 256, 0, stream>>>(
        (const float4*)L2, (float4*)band_ptr[2][0], (float4*)band_ptr[2][1],
        (float4*)band_ptr[2][2], (float4*)band_ptr[2][3], (float4*)L3,
        bfilts, lofilt, 8);
    scale_fused<5><<<8 * (4 + 1), 256, 0, stream>>>(
        (const float4*)L3, (float4*)band_ptr[3][0], (float4*)band_ptr[3][1],
        (float4*)band_ptr[3][2], (float4*)band_ptr[3][3], (float4*)out_lofinal,
        bfilts, lofilt, 0);
}

// Round 9
// 223.155 us; speedup vs baseline: 1.4234x; 1.4234x over previous
//
#include <hip/hip_runtime.h>

// Steerable pyramid, depthwise convs, NHWC fp32, C=16 (= 4 x float4).
// Branch-free convs over zero-padded workspace buffers.
// 2 output pixels per thread + __launch_bounds__(256,4): cap registers at
// 128/wave so >=4 waves/SIMD are resident (round-6's 4px tile used ~160
// unified VGPR+AGPR -> only ~3 waves/SIMD -> 63% latency stall).
// XCD-aware scheduling: n = blockIdx & 7, y swept in order per XCD.
// nt stores for d_out outputs; cached stores for ws lo buffers.

static __device__ __forceinline__ float4 f4z() { return make_float4(0.f, 0.f, 0.f, 0.f); }

static __device__ __forceinline__ float4 fmaf4(float f, float4 v, float4 a) {
    a.x = fmaf(f, v.x, a.x);
    a.y = fmaf(f, v.y, a.y);
    a.z = fmaf(f, v.z, a.z);
    a.w = fmaf(f, v.w, a.w);
    return a;
}

typedef __attribute__((ext_vector_type(4))) float f32x4;

static __device__ __forceinline__ void nt_store(float4* p, float4 v) {
    __builtin_nontemporal_store(*(const f32x4*)&v, (f32x4*)p);
}

// ---------------------------------------------------------------- pad helpers

__global__ __launch_bounds__(256) void pad_copy_img(
    const float4* __restrict__ src, float4* __restrict__ dst)
{
    const int W = 256, P = 4, Wp = 264;
    int n = blockIdx.x & 7;
    int q = blockIdx.x >> 3;                 // 1089 per n
    int e = q * 256 + threadIdx.x;           // < 264*264*4 exactly
    int c4 = e & 3;
    int pix = e >> 2;
    int yp = pix / Wp;
    int xp = pix - yp * Wp;
    int y = yp - P, x = xp - P;
    bool ok = ((unsigned)y < (unsigned)W) && ((unsigned)x < (unsigned)W);
    int yc = min(max(y, 0), W - 1), xc = min(max(x, 0), W - 1);
    float4 v = src[(((n * W + yc) * W + xc) << 2) + c4];
    if (!ok) v = f4z();
    dst[((size_t)n * Wp * Wp + pix) * 4 + c4] = v;
}

__global__ __launch_bounds__(256) void zero_pads_all(
    float4* __restrict__ L0, float4* __restrict__ L1,
    float4* __restrict__ L2, float4* __restrict__ L3)
{
    int b = blockIdx.x;
    float4* buf; int W;
    if (b < 1056)      { buf = L0; W = 256; }
    else if (b < 1600) { buf = L1; W = 128; b -= 1056; }
    else if (b < 1888) { buf = L2; W = 64;  b -= 1600; }
    else               { buf = L3; W = 32;  b -= 1888; }
    int Wp = W + 16;
    int perN = 16 * Wp + 16 * W;
    int tid = b * 256 + threadIdx.x;
    int c4 = tid & 3;
    int p  = tid >> 2;
    int n  = p / perN;
    int r  = p - n * perN;
    int y, x;
    if (r < 16 * Wp) {
        int row = r / Wp;
        x = r - row * Wp;
        y = (row < 8) ? row : (W + row);
    } else {
        int q = r - 16 * Wp;
        y = 8 + (q >> 4);
        int xi = q & 15;
        x = (xi < 8) ? xi : (Wp - 16 + xi);
    }
    buf[((size_t)(n * Wp + y) * Wp + x) * 4 + c4] = f4z();
}

// ---------------------------------------------------------------- convs

// hi0 + lo0 from padded image (pad 4, Wp=264). 2 px/thread.
// grid 8*512: n=b&7, q=b>>3; xh=q&1, y=q>>1.
__global__ __launch_bounds__(256, 4) void conv9_dual2(
    const float4* __restrict__ in,   // 264 wide, pad 4
    float4* __restrict__ hi0,        // flat 256 (d_out, nt)
    float4* __restrict__ lo0,        // 272 wide, pad 8 (ws, cached)
    const float* __restrict__ fh, const float* __restrict__ fl)
{
    const int Wp = 264;
    int n = blockIdx.x & 7;
    int q = blockIdx.x >> 3;
    int xh = q & 1, y = q >> 1;
    int t = threadIdx.x;
    int c4 = t & 3;
    int x0 = xh * 128 + ((t >> 2) & 63) * 2;
    const float4* rp = in + ((size_t)(n * Wp + y) * Wp + x0) * 4 + c4;
    const size_t rstep = (size_t)Wp * 4;

    float4 a00 = f4z(), a01 = f4z(), a10 = f4z(), a11 = f4z(); // [px][hi/lo]
    #pragma unroll 1
    for (int dy = 0; dy < 9; ++dy) {
        float4 v[10];
        #pragma unroll
        for (int j = 0; j < 10; ++j) v[j] = rp[j * 4];
        rp += rstep;
        const float* wh = fh + dy * 9;
        const float* wl = fl + dy * 9;
        #pragma unroll
        for (int dx = 0; dx < 9; ++dx) {
            float h = wh[dx], l = wl[dx];
            a00 = fmaf4(h, v[dx], a00);
            a01 = fmaf4(l, v[dx], a01);
            a10 = fmaf4(h, v[dx + 1], a10);
            a11 = fmaf4(l, v[dx + 1], a11);
        }
    }
    size_t hidx = ((size_t)(n * 256 + y) * 256 + x0) * 4 + c4;
    size_t lidx = ((size_t)(n * 272 + y + 8) * 272 + x0 + 8) * 4 + c4;
    nt_store(&hi0[hidx], a00);
    nt_store(&hi0[hidx + 4], a10);
    lo0[lidx] = a01;
    lo0[lidx + 4] = a11;
}

// Fused per-scale kernel, 2 px/thread.
// n=b&7, q=b>>3. q < bandsPerN: 9x9 quad bands; else 17x17 stride-2 down.
// Input: padded (pad 8) lo, Wp = W+16.
template <int LOGW>
__global__ __launch_bounds__(256, 4) void scale_fused2(
    const float4* __restrict__ in,
    float4* __restrict__ b0, float4* __restrict__ b1,
    float4* __restrict__ b2, float4* __restrict__ b3,
    float4* __restrict__ lo_out,
    const float* __restrict__ bf,    // 4*81 contiguous
    const float* __restrict__ lf,    // 17*17
    int outPad)
{
    const int W = 1 << LOGW, Wp = W + 16;
    const int bandsPerN = (W * W) >> 7;      // 2px/thread, 256 thr
    int n = blockIdx.x & 7;
    int q = blockIdx.x >> 3;
    int t = threadIdx.x;
    int c4 = t & 3;

    if (q < bandsPerN) {
        int x0, y;
        if constexpr (LOGW == 8) {
            int xh = q & 1; y = q >> 1;
            x0 = xh * 128 + ((t >> 2) & 63) * 2;
        } else {
            int xg2 = (t >> 2) & (W / 2 - 1);
            int ry = t >> (LOGW + 1);
            y = q * (1 << (7 - LOGW)) + ry;
            x0 = xg2 * 2;
        }
        const float4* rp = in + ((size_t)(n * Wp + y + 4) * Wp + (x0 + 4)) * 4 + c4;
        const size_t rstep = (size_t)Wp * 4;

        float4 a00 = f4z(), a01 = f4z(), a02 = f4z(), a03 = f4z(); // px0, filt 0..3
        float4 a10 = f4z(), a11 = f4z(), a12 = f4z(), a13 = f4z(); // px1
        #pragma unroll 1
        for (int dy = 0; dy < 9; ++dy) {
            float4 v[10];
            #pragma unroll
            for (int j = 0; j < 10; ++j) v[j] = rp[j * 4];
            rp += rstep;
            const float* wr = bf + dy * 9;
            #pragma unroll
            for (int dx = 0; dx < 9; ++dx) {
                float w0 = wr[dx], w1 = wr[81 + dx], w2 = wr[162 + dx], w3 = wr[243 + dx];
                a00 = fmaf4(w0, v[dx], a00);
                a01 = fmaf4(w1, v[dx], a01);
                a02 = fmaf4(w2, v[dx], a02);
                a03 = fmaf4(w3, v[dx], a03);
                a10 = fmaf4(w0, v[dx + 1], a10);
                a11 = fmaf4(w1, v[dx + 1], a11);
                a12 = fmaf4(w2, v[dx + 1], a12);
                a13 = fmaf4(w3, v[dx + 1], a13);
            }
        }
        size_t idx = ((size_t)(n * W + y) * W + x0) * 4 + c4;
        nt_store(&b0[idx], a00); nt_store(&b0[idx + 4], a10);
        nt_store(&b1[idx], a01); nt_store(&b1[idx + 4], a11);
        nt_store(&b2[idx], a02); nt_store(&b2[idx + 4], a12);
        nt_store(&b3[idx], a03); nt_store(&b3[idx + 4], a13);
    } else {
        const int Wo = W >> 1;
        int q2 = q - bandsPerN;
        int xg2 = (t >> 2) & (Wo / 2 - 1);
        int ry = t >> LOGW;                  // 2 + (LOGW-2)
        int yo = q2 * (1 << (8 - LOGW)) + ry;
        int xo0 = xg2 * 2;
        const float4* rp = in + ((size_t)(n * Wp + 2 * yo) * Wp + 2 * xo0) * 4 + c4;
        const size_t rstep = (size_t)Wp * 4;

        float4 ac0 = f4z(), ac1 = f4z();
        #pragma unroll 1
        for (int dy = 0; dy < 17; ++dy) {
            float4 v[19];
            #pragma unroll
            for (int j = 0; j < 19; ++j) v[j] = rp[j * 4];
            rp += rstep;
            const float* wp = lf + dy * 17;
            #pragma unroll
            for (int dx = 0; dx < 17; ++dx) {
                float w = wp[dx];
                ac0 = fmaf4(w, v[dx], ac0);
                ac1 = fmaf4(w, v[dx + 2], ac1);
            }
        }
        int W1 = Wo + 2 * outPad;
        size_t oidx = ((size_t)(n * W1 + yo + outPad) * W1 + xo0 + outPad) * 4 + c4;
        if (outPad == 0) {                   // final lo -> d_out
            nt_store(&lo_out[oidx], ac0);
            nt_store(&lo_out[oidx + 4], ac1);
        } else {                             // next lo level -> ws, cached
            lo_out[oidx] = ac0;
            lo_out[oidx + 4] = ac1;
        }
    }
}

// ---------------------------------------------------------------- launch

extern "C" void kernel_launch(void* const* d_in, const int* in_sizes, int n_in,
                              void* d_out, int out_size, void* d_ws, size_t ws_size,
                              hipStream_t stream) {
    const float* image   = (const float*)d_in[0];
    const float* lo0filt = (const float*)d_in[1];
    const float* hi0filt = (const float*)d_in[2];
    const float* lofilt  = (const float*)d_in[3];
    const float* bfilts  = (const float*)d_in[4];
    float* out = (float*)d_out;
    float* ws  = (float*)d_ws;

    const int N = 8, C = 16;
    size_t sz[5];
    const int Ws[5] = {256, 128, 64, 32, 16};
    for (int s = 0; s < 5; ++s) sz[s] = (size_t)N * Ws[s] * Ws[s] * C;

    // Workspace: P0 = image pad4 (264^2); L0..L3 = lo0..lo3 pad8.
    float* P0 = ws;
    float* L0 = P0 + (size_t)N * 264 * 264 * C;
    float* L1 = L0 + (size_t)N * 272 * 272 * C;
    float* L2 = L1 + (size_t)N * 144 * 144 * C;
    float* L3 = L2 + (size_t)N * 80 * 80 * C;

    // Output layout (reversed pyramid, flat):
    // [ lo_final | s=3 b=3..0 | s=2 b=3..0 | s=1 b=3..0 | s=0 b=3..0 | hi0 ]
    float* out_lofinal = out;
    size_t o = sz[4];
    float* band_ptr[4][4];
    for (int s = 3; s >= 0; --s)
        for (int b = 3; b >= 0; --b) { band_ptr[s][b] = out + o; o += sz[s]; }
    float* out_hi0 = out + o;

    // 1. zero pad borders of L0..L3
    zero_pads_all<<<2048, 256, 0, stream>>>(
        (float4*)L0, (float4*)L1, (float4*)L2, (float4*)L3);
    // 2. image -> P0 (pad 4)
    pad_copy_img<<<8 * 1089, 256, 0, stream>>>(
        (const float4*)image, (float4*)P0);
    // 3. hi0 (nt) + lo0 (cached)
    conv9_dual2<<<8 * 512, 256, 0, stream>>>(
        (const float4*)P0, (float4*)out_hi0, (float4*)L0, hi0filt, lo0filt);
    // 4..7. per-scale fused: bands_s + lo_{s+1}
    scale_fused2<8><<<8 * (512 + 128), 256, 0, stream>>>(
        (const float4*)L0, (float4*)band_ptr[0][0], (float4*)band_ptr[0][1],
        (float4*)band_ptr[0][2], (float4*)band_ptr[0][3], (float4*)L1,
        bfilts, lofilt, 8);
    scale_fused2<7><<<8 * (128 + 32), 256, 0, stream>>>(
        (const float4*)L1, (float4*)band_ptr[1][0], (float4*)band_ptr[1][1],
        (float4*)band_ptr[1][2], (float4*)band_ptr[1][3], (float4*)L2,
        bfilts, lofilt, 8);
    scale_fused2<6><<<8 * (32 + 8), 256, 0, stream>>>(
        (const float4*)L2, (float4*)band_ptr[2][0], (float4*)band_ptr[2][1],
        (float4*)band_ptr[2][2], (float4*)band_ptr[2][3], (float4*)L3,
        bfilts, lofilt, 8);
    scale_fused2<5><<<8 * (8 + 2), 256, 0, stream>>>(
        (const float4*)L3, (float4*)band_ptr[3][0], (float4*)band_ptr[3][1],
        (float4*)band_ptr[3][2], (float4*)band_ptr[3][3], (float4*)out_lofinal,
        bfilts, lofilt, 0);
}